// Round 1
// baseline (126.631 us; speedup 1.0000x reference)
//
#include <hip/hip_runtime.h>
#include <hip/hip_bf16.h>
#include <math.h>

#define B_ 16
#define T_ 12
#define N_ 325
#define C_ 64
#define K_ 8
#define L_ 3900            // N_*T_
#define M_ 249600          // C_*L_
#define LOG2PI_ 1.8378770664093453f

// ---------------- workspace layout (floats) ----------------
#define OFF_GLOG   0            // 128   (atomic-accumulated gamma logits)
#define OFF_S      128          // 128   (atomic-accumulated sum of P^2)
#define OFF_LOGGAM 256          // 128
#define OFF_PART   384          // 256
#define OFF_MUS    640          // 8192
#define OFF_ISIG   8832         // 8192
#define OFF_T1     17024        // 8192
#define OFF_P      25216        // 499200 = B*K*L
#define OFF_A      524416       // 3993600 = B*C*L  (normalized rep, [B][C][L])
#define OFF_AAUG   4518016      // 3993600          (normalized rep_aug)
// total = 8511616 floats = 34,046,464 bytes

// K1: per-(b,n) L2-normalize over C, write transposed [B][C][L]
__global__ __launch_bounds__(256) void knorm(const float* __restrict__ rep,
                                             const float* __restrict__ rep_aug,
                                             float* __restrict__ A,
                                             float* __restrict__ Aaug) {
    int bn = blockIdx.x;
    int b = bn / N_, n = bn - b * N_;
    const float* src = blockIdx.y ? rep_aug : rep;
    float* dst = blockIdx.y ? Aaug : A;
    __shared__ float lds[T_ * 64];
    __shared__ float sc[T_];
    int tid = threadIdx.x;
    for (int idx = tid; idx < T_ * 64; idx += 256) {
        int t = idx >> 6, c = idx & 63;
        lds[idx] = src[((b * T_ + t) * N_ + n) * C_ + c];
    }
    __syncthreads();
    int lane = tid & 63, wave = tid >> 6;
    #pragma unroll
    for (int i = 0; i < 3; ++i) {
        int t = wave + (i << 2);          // waves 0..3 cover t = 0..11
        float x = lds[t * 64 + lane];
        float ss = x * x;
        #pragma unroll
        for (int m = 1; m < 64; m <<= 1) ss += __shfl_xor(ss, m);
        if (lane == 0) sc[t] = 1.0f / fmaxf(sqrtf(ss), 1e-12f);
    }
    __syncthreads();
    for (int idx = tid; idx < 64 * T_; idx += 256) {
        int c = idx / T_, t = idx - c * T_;
        dst[(b * C_ + c) * L_ + n * T_ + t] = lds[t * 64 + c] * sc[t];
    }
}

// K2: gamma logits glog[b][k] = sum_m Aaug[b][m] * Wg[k][m], m = c*L+l
__global__ __launch_bounds__(256) void kgamma(const float* __restrict__ Aaug,
                                              const float* __restrict__ Wg,
                                              float* __restrict__ glog) {
    float acc[B_][K_];
    #pragma unroll
    for (int b = 0; b < B_; ++b)
        #pragma unroll
        for (int k = 0; k < K_; ++k) acc[b][k] = 0.0f;

    for (int m = blockIdx.x * 256 + threadIdx.x; m < M_; m += 256 * 256) {
        float w[K_], a[B_];
        #pragma unroll
        for (int k = 0; k < K_; ++k) w[k] = Wg[k * M_ + m];
        #pragma unroll
        for (int b = 0; b < B_; ++b) a[b] = Aaug[b * M_ + m];
        #pragma unroll
        for (int b = 0; b < B_; ++b)
            #pragma unroll
            for (int k = 0; k < K_; ++k)
                acc[b][k] = fmaf(a[b], w[k], acc[b][k]);
    }
    __shared__ float red[4][128];
    int lane = threadIdx.x & 63, wave = threadIdx.x >> 6;
    #pragma unroll
    for (int b = 0; b < B_; ++b)
        #pragma unroll
        for (int k = 0; k < K_; ++k) {
            float v = acc[b][k];
            #pragma unroll
            for (int m = 1; m < 64; m <<= 1) v += __shfl_xor(v, m);
            if (lane == 0) red[wave][b * K_ + k] = v;
        }
    __syncthreads();
    if (threadIdx.x < 128) {
        float s = red[0][threadIdx.x] + red[1][threadIdx.x] +
                  red[2][threadIdx.x] + red[3][threadIdx.x];
        atomicAdd(glog + threadIdx.x, s);
    }
}

// K3: loggam = log_softmax(glog) per b. 128 threads.
__global__ void ksoftmax(const float* __restrict__ glog, float* __restrict__ loggam) {
    int tid = threadIdx.x;          // b*8+k
    int b = tid >> 3;
    __shared__ float l[128];
    float v = glog[tid];
    l[tid] = v;
    __syncthreads();
    float mx = -1e30f;
    #pragma unroll
    for (int k = 0; k < K_; ++k) mx = fmaxf(mx, l[b * K_ + k]);
    float s = 0.0f;
    #pragma unroll
    for (int k = 0; k < K_; ++k) s += expf(l[b * K_ + k] - mx);
    loggam[tid] = v - mx - logf(s);
}

// K4: per-(b,c) conv1d k=1: mus, inv_sigma, t1
__global__ __launch_bounds__(256) void kconv(const float* __restrict__ Aaug,
                                             const float* __restrict__ Wmu,
                                             const float* __restrict__ bmu,
                                             const float* __restrict__ Wsg,
                                             const float* __restrict__ bsg,
                                             float* __restrict__ mus,
                                             float* __restrict__ isig,
                                             float* __restrict__ t1) {
    int bc = blockIdx.x;                   // b*64 + c ; Aaug row offset = bc*L
    const float* arow = Aaug + (size_t)bc * L_;
    float am[K_], as[K_];
    #pragma unroll
    for (int k = 0; k < K_; ++k) { am[k] = 0.0f; as[k] = 0.0f; }
    for (int l = threadIdx.x; l < L_; l += 256) {
        float a = arow[l];
        #pragma unroll
        for (int k = 0; k < K_; ++k) {
            am[k] = fmaf(Wmu[k * L_ + l], a, am[k]);
            as[k] = fmaf(Wsg[k * L_ + l], a, as[k]);
        }
    }
    __shared__ float red[4][16];
    int lane = threadIdx.x & 63, wave = threadIdx.x >> 6;
    #pragma unroll
    for (int k = 0; k < K_; ++k) {
        float v = am[k];
        #pragma unroll
        for (int m = 1; m < 64; m <<= 1) v += __shfl_xor(v, m);
        if (lane == 0) red[wave][k] = v;
        float u = as[k];
        #pragma unroll
        for (int m = 1; m < 64; m <<= 1) u += __shfl_xor(u, m);
        if (lane == 0) red[wave][8 + k] = u;
    }
    __syncthreads();
    if (threadIdx.x < 16) {
        float s = red[0][threadIdx.x] + red[1][threadIdx.x] +
                  red[2][threadIdx.x] + red[3][threadIdx.x];
        int k = threadIdx.x & 7;
        if (threadIdx.x < 8) {
            mus[bc * K_ + k] = s + bmu[k];
        } else {
            float logit = s + bsg[k];
            isig[bc * K_ + k] = expf(-logit);
            t1[bc * K_ + k] = -logit - 0.5f * LOG2PI_;
        }
    }
}

// K5: P[b][k][l] = prod_c logp ; S[b][k] += sum_l P^2
__global__ __launch_bounds__(256) void kprod(const float* __restrict__ A,
                                             const float* __restrict__ mus,
                                             const float* __restrict__ isig,
                                             const float* __restrict__ t1,
                                             float* __restrict__ P,
                                             float* __restrict__ S) {
    int b = blockIdx.x / 61, lc = blockIdx.x - b * 61;
    int l0 = lc * 64;
    __shared__ float ldsA[64][64];
    __shared__ float ldsMu[512], ldsIs[512], ldsT1[512];
    int tid = threadIdx.x;
    for (int idx = tid; idx < 4096; idx += 256) {
        int c = idx >> 6, ll = idx & 63;
        int l = l0 + ll;
        ldsA[c][ll] = (l < L_) ? A[(b * C_ + c) * L_ + l] : 0.0f;
    }
    for (int idx = tid; idx < 512; idx += 256) {
        ldsMu[idx] = mus[b * 512 + idx];
        ldsIs[idx] = isig[b * 512 + idx];
        ldsT1[idx] = t1[b * 512 + idx];
    }
    __syncthreads();
    int lane = tid & 63, kg = tid >> 6;     // wave == kg, lanes = l
    int l = l0 + lane;
    bool valid = l < L_;
    int k0 = kg * 2, k1 = k0 + 1;
    float p0 = 1.0f, p1 = 1.0f;
    #pragma unroll 8
    for (int c = 0; c < 64; ++c) {
        float a = ldsA[c][lane];
        float z0 = (a - ldsMu[c * 8 + k0]) * ldsIs[c * 8 + k0];
        p0 *= ldsT1[c * 8 + k0] - 0.5f * z0 * z0;
        float z1 = (a - ldsMu[c * 8 + k1]) * ldsIs[c * 8 + k1];
        p1 *= ldsT1[c * 8 + k1] - 0.5f * z1 * z1;
    }
    if (!valid) { p0 = 0.0f; p1 = 0.0f; }
    if (valid) {
        P[(b * K_ + k0) * L_ + l] = p0;
        P[(b * K_ + k1) * L_ + l] = p1;
    }
    float v0 = p0 * p0, v1 = p1 * p1;
    #pragma unroll
    for (int m = 1; m < 64; m <<= 1) { v0 += __shfl_xor(v0, m); v1 += __shfl_xor(v1, m); }
    if (lane == 0) { atomicAdd(&S[b * K_ + k0], v0); atomicAdd(&S[b * K_ + k1], v1); }
}

// K6: per-(b,l) LSE over k -> block partial sums
__global__ __launch_bounds__(256) void kloss(const float* __restrict__ P,
                                             const float* __restrict__ S,
                                             const float* __restrict__ loggam,
                                             float* __restrict__ part) {
    int b = blockIdx.x >> 4, ch = blockIdx.x & 15;
    int l = ch * 256 + threadIdx.x;
    float ll = 0.0f;
    if (l < L_) {
        float v[K_];
        float mx = -1e30f;
        #pragma unroll
        for (int k = 0; k < K_; ++k) {
            float invn = 1.0f / fmaxf(sqrtf(S[b * K_ + k]), 1e-12f);
            v[k] = P[(b * K_ + k) * L_ + l] * invn + loggam[b * K_ + k];
            mx = fmaxf(mx, v[k]);
        }
        float s = 0.0f;
        #pragma unroll
        for (int k = 0; k < K_; ++k) s += expf(v[k] - mx);
        ll = mx + logf(s);
    }
    #pragma unroll
    for (int m = 1; m < 64; m <<= 1) ll += __shfl_xor(ll, m);
    __shared__ float red[4];
    int lane = threadIdx.x & 63, wave = threadIdx.x >> 6;
    if (lane == 0) red[wave] = ll;
    __syncthreads();
    if (threadIdx.x == 0) part[blockIdx.x] = red[0] + red[1] + red[2] + red[3];
}

// K7: final reduce (deterministic, double)
__global__ void kfinal(const float* __restrict__ part, float* __restrict__ out) {
    double v = (double)part[threadIdx.x];
    #pragma unroll
    for (int m = 1; m < 64; m <<= 1) v += __shfl_xor(v, m);
    __shared__ double red[4];
    int lane = threadIdx.x & 63, wave = threadIdx.x >> 6;
    if (lane == 0) red[wave] = v;
    __syncthreads();
    if (threadIdx.x == 0)
        out[0] = (float)(-(red[0] + red[1] + red[2] + red[3]) / ((double)B_ * (double)L_));
}

extern "C" void kernel_launch(void* const* d_in, const int* in_sizes, int n_in,
                              void* d_out, int out_size, void* d_ws, size_t ws_size,
                              hipStream_t stream) {
    const float* rep     = (const float*)d_in[0];
    const float* rep_aug = (const float*)d_in[1];
    const float* Wg      = (const float*)d_in[2];
    const float* Wmu     = (const float*)d_in[3];
    const float* bmu     = (const float*)d_in[4];
    const float* Wsg     = (const float*)d_in[5];
    const float* bsg     = (const float*)d_in[6];
    float* out = (float*)d_out;
    float* ws  = (float*)d_ws;

    float* glog   = ws + OFF_GLOG;
    float* S      = ws + OFF_S;
    float* loggam = ws + OFF_LOGGAM;
    float* part   = ws + OFF_PART;
    float* mus    = ws + OFF_MUS;
    float* isig   = ws + OFF_ISIG;
    float* t1     = ws + OFF_T1;
    float* P      = ws + OFF_P;
    float* A      = ws + OFF_A;
    float* Aaug   = ws + OFF_AAUG;

    // zero the atomic accumulators (glog + S are the first 256 floats)
    hipMemsetAsync(ws, 0, 256 * sizeof(float), stream);

    knorm<<<dim3(B_ * N_, 2), 256, 0, stream>>>(rep, rep_aug, A, Aaug);
    kgamma<<<256, 256, 0, stream>>>(Aaug, Wg, glog);
    ksoftmax<<<1, 128, 0, stream>>>(glog, loggam);
    kconv<<<B_ * C_, 256, 0, stream>>>(Aaug, Wmu, bmu, Wsg, bsg, mus, isig, t1);
    kprod<<<B_ * 61, 256, 0, stream>>>(A, mus, isig, t1, P, S);
    kloss<<<B_ * 16, 256, 0, stream>>>(P, S, loggam, part);
    kfinal<<<1, 256, 0, stream>>>(part, out);
}

// Round 2
// 110.733 us; speedup vs baseline: 1.1436x; 1.1436x over previous
//
#include <hip/hip_runtime.h>
#include <hip/hip_bf16.h>
#include <math.h>

#define B_ 16
#define T_ 12
#define N_ 325
#define C_ 64
#define K_ 8
#define L_ 3900            // N_*T_
#define M_ 249600          // C_*L_
#define M4_ 62400          // M_/4
#define LCH_ 61            // ceil(L_/64)
#define NG_ 8              // n-group size in knorm
#define NGRP_ 41           // ceil(N_/NG_)
#define LOG2PI_ 1.8378770664093453f

// ---------------- workspace layout (floats) ----------------
#define OFF_GLOG   0            // 128
#define OFF_S      128          // 128  (atomic, zeroed each call)
#define OFF_LOGGAM 256          // 128
#define OFF_PART   384          // 256
#define OFF_MUS    640          // 8192
#define OFF_ISIG   8832         // 8192
#define OFF_T1     17024        // 8192
#define OFF_P      25216        // 499200 = B*K*L
#define OFF_A      524416       // 3993600 = B*C*L
#define OFF_AAUG   4518016      // 3993600
#define OFF_GPART  8511616      // 124800 = 975*128
#define OFF_CONVP  8636416      // 998400 = 61*16384
// total = 9634816 floats = 38.54 MB

// K1: per-(b, n-group) L2-normalize over C, write transposed [B][C][L]
__global__ __launch_bounds__(256) void knorm(const float* __restrict__ rep,
                                             const float* __restrict__ rep_aug,
                                             float* __restrict__ A,
                                             float* __restrict__ Aaug) {
    int bg = blockIdx.x;
    int b = bg / NGRP_, ng = bg - b * NGRP_;
    int n0 = ng * NG_;
    int nv = N_ - n0; if (nv > NG_) nv = NG_;
    int vq = nv * T_;                       // valid q count (q = nn*T + t)
    const float* src = blockIdx.y ? rep_aug : rep;
    float* dst = blockIdx.y ? Aaug : A;
    __shared__ float lds[96 * 65];
    __shared__ float sc[96];
    int tid = threadIdx.x;
    const float4* src4 = (const float4*)src;
    // load 96 x 64 tile (float4 over c)
    for (int i4 = tid; i4 < 1536; i4 += 256) {
        int p = i4 >> 4;                    // q = nn*12 + t, 0..95
        int c4 = i4 & 15;
        int nn = p / T_, t = p - nn * T_;
        float4 v = make_float4(0.f, 0.f, 0.f, 0.f);
        if (nn < nv) v = src4[(size_t)((b * T_ + t) * N_ + (n0 + nn)) * 16 + c4];
        int base = p * 65 + c4 * 4;
        lds[base] = v.x; lds[base + 1] = v.y; lds[base + 2] = v.z; lds[base + 3] = v.w;
    }
    __syncthreads();
    int lane = tid & 63, wv = tid >> 6;
    #pragma unroll 4
    for (int i = 0; i < 24; ++i) {
        int p = wv * 24 + i;
        float x = lds[p * 65 + lane];
        float ss = x * x;
        #pragma unroll
        for (int m = 1; m < 64; m <<= 1) ss += __shfl_xor(ss, m);
        if (lane == 0) sc[p] = 1.0f / fmaxf(sqrtf(ss), 1e-12f);
    }
    __syncthreads();
    // write: per c row, q contiguous (up to 96 consecutive floats)
    for (int idx = tid; idx < 64 * 96; idx += 256) {
        int c = idx / 96, q = idx - c * 96;
        if (q < vq)
            dst[(size_t)(b * C_ + c) * L_ + n0 * T_ + q] = lds[q * 65 + c] * sc[q];
    }
}

// K2: gamma logit partials. Block = 64 float4-m's; waves split B. 975 blocks.
__global__ __launch_bounds__(256) void kgamma(const float* __restrict__ Aaug,
                                              const float* __restrict__ Wg,
                                              float* __restrict__ gpart) {
    const float4* A4 = (const float4*)Aaug;
    const float4* W4 = (const float4*)Wg;
    int lane = threadIdx.x & 63, wv = threadIdx.x >> 6;
    int m4 = blockIdx.x * 64 + lane;        // < 62400 always (975*64)
    float4 w[K_];
    #pragma unroll
    for (int k = 0; k < K_; ++k) w[k] = W4[(size_t)k * M4_ + m4];
    float acc[4][K_];
    #pragma unroll
    for (int bb = 0; bb < 4; ++bb) {
        float4 a = A4[(size_t)(wv * 4 + bb) * M4_ + m4];
        #pragma unroll
        for (int k = 0; k < K_; ++k)
            acc[bb][k] = a.x * w[k].x + a.y * w[k].y + a.z * w[k].z + a.w * w[k].w;
    }
    __shared__ float red[4][32];
    #pragma unroll
    for (int bb = 0; bb < 4; ++bb)
        #pragma unroll
        for (int k = 0; k < K_; ++k) {
            float v = acc[bb][k];
            #pragma unroll
            for (int m = 1; m < 64; m <<= 1) v += __shfl_xor(v, m);
            if (lane == 0) red[wv][bb * 8 + k] = v;
        }
    __syncthreads();
    if (threadIdx.x < 128)
        gpart[(size_t)blockIdx.x * 128 + threadIdx.x] = ((float*)red)[threadIdx.x];
}

// K2b: reduce gpart over 975 blocks -> glog[128]
__global__ __launch_bounds__(256) void kgred(const float* __restrict__ gpart,
                                             float* __restrict__ glog) {
    int o = blockIdx.x;                     // 0..127
    float s = 0.0f;
    for (int i = threadIdx.x; i < 975; i += 256) s += gpart[(size_t)i * 128 + o];
    #pragma unroll
    for (int m = 1; m < 64; m <<= 1) s += __shfl_xor(s, m);
    __shared__ float r[4];
    int lane = threadIdx.x & 63, wv = threadIdx.x >> 6;
    if (lane == 0) r[wv] = s;
    __syncthreads();
    if (threadIdx.x == 0) glog[o] = r[0] + r[1] + r[2] + r[3];
}

// K3: log-softmax per b
__global__ void ksoftmax(const float* __restrict__ glog, float* __restrict__ loggam) {
    int tid = threadIdx.x;                  // b*8+k
    int b = tid >> 3;
    __shared__ float l[128];
    float v = glog[tid];
    l[tid] = v;
    __syncthreads();
    float mx = -1e30f;
    #pragma unroll
    for (int k = 0; k < K_; ++k) mx = fmaxf(mx, l[b * K_ + k]);
    float s = 0.0f;
    #pragma unroll
    for (int k = 0; k < K_; ++k) s += expf(l[b * K_ + k] - mx);
    loggam[tid] = v - mx - logf(s);
}

// K4: conv partials. Block = (b, l-chunk of 64). W read once total.
__global__ __launch_bounds__(256) void kconv(const float* __restrict__ Aaug,
                                             const float* __restrict__ Wmu,
                                             const float* __restrict__ Wsg,
                                             float* __restrict__ convp) {
    int b = blockIdx.x / LCH_, lc = blockIdx.x - b * LCH_;
    int l0 = lc * 64;
    __shared__ float ldsA[64 * 65];
    __shared__ float ldsW[16 * 64];
    int tid = threadIdx.x;
    for (int idx = tid; idx < 4096; idx += 256) {
        int c = idx >> 6, ll = idx & 63;
        int l = l0 + ll;
        ldsA[c * 65 + ll] = (l < L_) ? Aaug[(size_t)(b * C_ + c) * L_ + l] : 0.0f;
    }
    for (int idx = tid; idx < 1024; idx += 256) {
        int r = idx >> 6, ll = idx & 63;
        int l = l0 + ll;
        float w = 0.0f;
        if (l < L_) w = (r < 8) ? Wmu[r * L_ + l] : Wsg[(r - 8) * L_ + l];
        ldsW[r * 64 + ll] = w;
    }
    __syncthreads();
    int c = tid & 63, kk = tid >> 6;        // thread owns (c, 4 k's)
    const float* w0 = &ldsW[(kk * 4 + 0) * 64];
    const float* w1 = &ldsW[(kk * 4 + 1) * 64];
    const float* w2 = &ldsW[(kk * 4 + 2) * 64];
    const float* w3 = &ldsW[(kk * 4 + 3) * 64];
    float a0 = 0.f, a1 = 0.f, a2 = 0.f, a3 = 0.f;
    #pragma unroll 8
    for (int l = 0; l < 64; ++l) {
        float a = ldsA[c * 65 + l];
        a0 = fmaf(a, w0[l], a0);
        a1 = fmaf(a, w1[l], a1);
        a2 = fmaf(a, w2[l], a2);
        a3 = fmaf(a, w3[l], a3);
    }
    float* dst = convp + (size_t)lc * 16384 + b * 1024 + c * 16 + kk * 4;
    dst[0] = a0; dst[1] = a1; dst[2] = a2; dst[3] = a3;
}

// K4b: finish conv: sum 61 partials, add bias, exp
__global__ __launch_bounds__(256) void kconvfin(const float* __restrict__ convp,
                                                const float* __restrict__ bmu,
                                                const float* __restrict__ bsg,
                                                float* __restrict__ mus,
                                                float* __restrict__ isig,
                                                float* __restrict__ t1) {
    int o = blockIdx.x * 256 + threadIdx.x;  // 0..16383 = b*1024 + c*16 + kk
    float s = 0.0f;
    #pragma unroll 8
    for (int lc = 0; lc < LCH_; ++lc) s += convp[(size_t)lc * 16384 + o];
    int bc = o >> 4, kk = o & 15;
    int k = kk & 7;
    if (kk < 8) {
        mus[bc * 8 + k] = s + bmu[k];
    } else {
        float logit = s + bsg[k];
        isig[bc * 8 + k] = expf(-logit);
        t1[bc * 8 + k] = -logit - 0.5f * LOG2PI_;
    }
}

// K5: P[b][k][l] = prod_c logp ; S[b][k] += sum_l P^2
__global__ __launch_bounds__(256) void kprod(const float* __restrict__ A,
                                             const float* __restrict__ mus,
                                             const float* __restrict__ isig,
                                             const float* __restrict__ t1,
                                             float* __restrict__ P,
                                             float* __restrict__ S) {
    int b = blockIdx.x / LCH_, lc = blockIdx.x - b * LCH_;
    int l0 = lc * 64;
    __shared__ float ldsA[64 * 64];
    __shared__ float ldsMu[512], ldsIs[512], ldsT1[512];
    int tid = threadIdx.x;
    for (int idx = tid; idx < 4096; idx += 256) {
        int c = idx >> 6, ll = idx & 63;
        int l = l0 + ll;
        ldsA[c * 64 + ll] = (l < L_) ? A[(size_t)(b * C_ + c) * L_ + l] : 0.0f;
    }
    for (int idx = tid; idx < 512; idx += 256) {
        ldsMu[idx] = mus[b * 512 + idx];
        ldsIs[idx] = isig[b * 512 + idx];
        ldsT1[idx] = t1[b * 512 + idx];
    }
    __syncthreads();
    int lane = tid & 63, kg = tid >> 6;
    int l = l0 + lane;
    bool valid = l < L_;
    int k0 = kg * 2, k1 = k0 + 1;
    float p0 = 1.0f, p1 = 1.0f;
    #pragma unroll 8
    for (int c = 0; c < 64; ++c) {
        float a = ldsA[c * 64 + lane];
        float z0 = (a - ldsMu[c * 8 + k0]) * ldsIs[c * 8 + k0];
        p0 *= ldsT1[c * 8 + k0] - 0.5f * z0 * z0;
        float z1 = (a - ldsMu[c * 8 + k1]) * ldsIs[c * 8 + k1];
        p1 *= ldsT1[c * 8 + k1] - 0.5f * z1 * z1;
    }
    if (!valid) { p0 = 0.0f; p1 = 0.0f; }
    if (valid) {
        P[(size_t)(b * K_ + k0) * L_ + l] = p0;
        P[(size_t)(b * K_ + k1) * L_ + l] = p1;
    }
    float v0 = p0 * p0, v1 = p1 * p1;
    #pragma unroll
    for (int m = 1; m < 64; m <<= 1) { v0 += __shfl_xor(v0, m); v1 += __shfl_xor(v1, m); }
    if (lane == 0) { atomicAdd(&S[b * K_ + k0], v0); atomicAdd(&S[b * K_ + k1], v1); }
}

// K6: per-(b,l) LSE over k -> block partials
__global__ __launch_bounds__(256) void kloss(const float* __restrict__ P,
                                             const float* __restrict__ S,
                                             const float* __restrict__ loggam,
                                             float* __restrict__ part) {
    int b = blockIdx.x >> 4, ch = blockIdx.x & 15;
    int l = ch * 256 + threadIdx.x;
    float ll = 0.0f;
    if (l < L_) {
        float v[K_];
        float mx = -1e30f;
        #pragma unroll
        for (int k = 0; k < K_; ++k) {
            float invn = 1.0f / fmaxf(sqrtf(S[b * K_ + k]), 1e-12f);
            v[k] = P[(size_t)(b * K_ + k) * L_ + l] * invn + loggam[b * K_ + k];
            mx = fmaxf(mx, v[k]);
        }
        float s = 0.0f;
        #pragma unroll
        for (int k = 0; k < K_; ++k) s += expf(v[k] - mx);
        ll = mx + logf(s);
    }
    #pragma unroll
    for (int m = 1; m < 64; m <<= 1) ll += __shfl_xor(ll, m);
    __shared__ float red[4];
    int lane = threadIdx.x & 63, wave = threadIdx.x >> 6;
    if (lane == 0) red[wave] = ll;
    __syncthreads();
    if (threadIdx.x == 0) part[blockIdx.x] = red[0] + red[1] + red[2] + red[3];
}

// K7: final reduce
__global__ void kfinal(const float* __restrict__ part, float* __restrict__ out) {
    double v = (double)part[threadIdx.x];
    #pragma unroll
    for (int m = 1; m < 64; m <<= 1) v += __shfl_xor(v, m);
    __shared__ double red[4];
    int lane = threadIdx.x & 63, wave = threadIdx.x >> 6;
    if (lane == 0) red[wave] = v;
    __syncthreads();
    if (threadIdx.x == 0)
        out[0] = (float)(-(red[0] + red[1] + red[2] + red[3]) / ((double)B_ * (double)L_));
}

extern "C" void kernel_launch(void* const* d_in, const int* in_sizes, int n_in,
                              void* d_out, int out_size, void* d_ws, size_t ws_size,
                              hipStream_t stream) {
    const float* rep     = (const float*)d_in[0];
    const float* rep_aug = (const float*)d_in[1];
    const float* Wg      = (const float*)d_in[2];
    const float* Wmu     = (const float*)d_in[3];
    const float* bmu     = (const float*)d_in[4];
    const float* Wsg     = (const float*)d_in[5];
    const float* bsg     = (const float*)d_in[6];
    float* out = (float*)d_out;
    float* ws  = (float*)d_ws;

    float* glog   = ws + OFF_GLOG;
    float* S      = ws + OFF_S;
    float* loggam = ws + OFF_LOGGAM;
    float* part   = ws + OFF_PART;
    float* mus    = ws + OFF_MUS;
    float* isig   = ws + OFF_ISIG;
    float* t1     = ws + OFF_T1;
    float* P      = ws + OFF_P;
    float* A      = ws + OFF_A;
    float* Aaug   = ws + OFF_AAUG;
    float* gpart  = ws + OFF_GPART;
    float* convp  = ws + OFF_CONVP;

    // zero the atomic accumulators (glog unused-zero + S)
    hipMemsetAsync(ws, 0, 256 * sizeof(float), stream);

    knorm<<<dim3(B_ * NGRP_, 2), 256, 0, stream>>>(rep, rep_aug, A, Aaug);
    kgamma<<<975, 256, 0, stream>>>(Aaug, Wg, gpart);
    kgred<<<128, 256, 0, stream>>>(gpart, glog);
    ksoftmax<<<1, 128, 0, stream>>>(glog, loggam);
    kconv<<<B_ * LCH_, 256, 0, stream>>>(Aaug, Wmu, Wsg, convp);
    kconvfin<<<64, 256, 0, stream>>>(convp, bmu, bsg, mus, isig, t1);
    kprod<<<B_ * LCH_, 256, 0, stream>>>(A, mus, isig, t1, P, S);
    kloss<<<B_ * 16, 256, 0, stream>>>(P, S, loggam, part);
    kfinal<<<1, 256, 0, stream>>>(part, out);
}

// Round 3
// 85.094 us; speedup vs baseline: 1.4881x; 1.3013x over previous
//
#include <hip/hip_runtime.h>
#include <hip/hip_bf16.h>
#include <math.h>

#define B_ 16
#define T_ 12
#define N_ 325
#define C_ 64
#define K_ 8
#define L_ 3900            // N_*T_
#define M_ 249600          // C_*L_
#define M4_ 62400          // M_/4
#define LCH_ 61            // ceil(L_/64)
#define NG_ 8              // n-group size in knorm
#define NGRP_ 41           // ceil(N_/NG_)
#define LOG2PI_ 1.8378770664093453f

// ---------------- workspace layout (floats) ----------------
#define OFF_LOGGAM 0            // 128
#define OFF_INVN   128          // 128
#define OFF_PART   256          // 256
#define OFF_MUS    512          // 8192
#define OFF_ISIG   8704         // 8192
#define OFF_T1     16896        // 8192
#define OFF_SPART  25088        // 7808 = 128*61
#define OFF_P      32896        // 499200 = B*K*L
#define OFF_AAUG   532096       // 3993600 = B*C*L
#define OFF_GPART  4525696      // 124800 = 128*975 (transposed)
#define OFF_CONVP  4650496      // 998400 = 61*16384
// total = 5648896 floats = 22.6 MB

// K1: per-(b, n-group) L2-normalize rep_aug over C, write transposed [B][C][L]
__global__ __launch_bounds__(256) void knorm(const float* __restrict__ rep_aug,
                                             float* __restrict__ Aaug) {
    int bg = blockIdx.x;
    int b = bg / NGRP_, ng = bg - b * NGRP_;
    int n0 = ng * NG_;
    int nv = N_ - n0; if (nv > NG_) nv = NG_;
    int vq = nv * T_;                       // valid q count (q = nn*T + t)
    __shared__ float lds[96 * 65];
    __shared__ float sc[96];
    int tid = threadIdx.x;
    const float4* src4 = (const float4*)rep_aug;
    for (int i4 = tid; i4 < 1536; i4 += 256) {
        int p = i4 >> 4;                    // q = nn*12 + t, 0..95
        int c4 = i4 & 15;
        int nn = p / T_, t = p - nn * T_;
        float4 v = make_float4(0.f, 0.f, 0.f, 0.f);
        if (nn < nv) v = src4[(size_t)((b * T_ + t) * N_ + (n0 + nn)) * 16 + c4];
        int base = p * 65 + c4 * 4;
        lds[base] = v.x; lds[base + 1] = v.y; lds[base + 2] = v.z; lds[base + 3] = v.w;
    }
    __syncthreads();
    int lane = tid & 63, wv = tid >> 6;
    #pragma unroll 4
    for (int i = 0; i < 24; ++i) {
        int p = wv * 24 + i;
        float x = lds[p * 65 + lane];
        float ss = x * x;
        #pragma unroll
        for (int m = 1; m < 64; m <<= 1) ss += __shfl_xor(ss, m);
        if (lane == 0) sc[p] = 1.0f / fmaxf(sqrtf(ss), 1e-12f);
    }
    __syncthreads();
    for (int idx = tid; idx < 64 * 96; idx += 256) {
        int c = idx / 96, q = idx - c * 96;
        if (q < vq)
            Aaug[(size_t)(b * C_ + c) * L_ + n0 * T_ + q] = lds[q * 65 + c] * sc[q];
    }
}

// K2: gamma logit partials -> transposed gpartT[o][blk], o = b*8+k
__global__ __launch_bounds__(256) void kgamma(const float* __restrict__ Aaug,
                                              const float* __restrict__ Wg,
                                              float* __restrict__ gpartT) {
    const float4* A4 = (const float4*)Aaug;
    const float4* W4 = (const float4*)Wg;
    int lane = threadIdx.x & 63, wv = threadIdx.x >> 6;
    int m4 = blockIdx.x * 64 + lane;        // < 62400 always (975*64)
    float4 w[K_];
    #pragma unroll
    for (int k = 0; k < K_; ++k) w[k] = W4[(size_t)k * M4_ + m4];
    float acc[4][K_];
    #pragma unroll
    for (int bb = 0; bb < 4; ++bb) {
        float4 a = A4[(size_t)(wv * 4 + bb) * M4_ + m4];
        #pragma unroll
        for (int k = 0; k < K_; ++k)
            acc[bb][k] = a.x * w[k].x + a.y * w[k].y + a.z * w[k].z + a.w * w[k].w;
    }
    __shared__ float red[4][32];
    #pragma unroll
    for (int bb = 0; bb < 4; ++bb)
        #pragma unroll
        for (int k = 0; k < K_; ++k) {
            float v = acc[bb][k];
            #pragma unroll
            for (int m = 1; m < 64; m <<= 1) v += __shfl_xor(v, m);
            if (lane == 0) red[wv][bb * 8 + k] = v;
        }
    __syncthreads();
    // flattened red index tid = wv*32+bb*8+k  ->  o = b*8+k = tid (b = wv*4+bb)
    if (threadIdx.x < 128)
        gpartT[(size_t)threadIdx.x * 975 + blockIdx.x] = ((float*)red)[threadIdx.x];
}

// K2b: fused reduce + log-softmax. Block = b (16 blocks, 512 thr).
__global__ __launch_bounds__(512) void kgsm(const float* __restrict__ gpartT,
                                            float* __restrict__ loggam) {
    int b = blockIdx.x;
    int lane = threadIdx.x & 63, k = threadIdx.x >> 6;   // 8 waves = 8 k's
    const float* src = gpartT + (size_t)(b * 8 + k) * 975;
    float s = 0.0f;
    for (int i = lane; i < 975; i += 64) s += src[i];
    #pragma unroll
    for (int m = 1; m < 64; m <<= 1) s += __shfl_xor(s, m);
    __shared__ float red[8];
    if (lane == 0) red[k] = s;
    __syncthreads();
    if (threadIdx.x < 8) {
        float mx = -1e30f;
        #pragma unroll
        for (int j = 0; j < 8; ++j) mx = fmaxf(mx, red[j]);
        float sum = 0.0f;
        #pragma unroll
        for (int j = 0; j < 8; ++j) sum += expf(red[j] - mx);
        loggam[b * 8 + threadIdx.x] = red[threadIdx.x] - mx - logf(sum);
    }
}

// K4: conv partials. Block = (b, l-chunk of 64).
__global__ __launch_bounds__(256) void kconv(const float* __restrict__ Aaug,
                                             const float* __restrict__ Wmu,
                                             const float* __restrict__ Wsg,
                                             float* __restrict__ convp) {
    int b = blockIdx.x / LCH_, lc = blockIdx.x - b * LCH_;
    int l0 = lc * 64;
    __shared__ float ldsA[64 * 65];
    __shared__ float ldsW[16 * 64];
    int tid = threadIdx.x;
    for (int idx = tid; idx < 4096; idx += 256) {
        int c = idx >> 6, ll = idx & 63;
        int l = l0 + ll;
        ldsA[c * 65 + ll] = (l < L_) ? Aaug[(size_t)(b * C_ + c) * L_ + l] : 0.0f;
    }
    for (int idx = tid; idx < 1024; idx += 256) {
        int r = idx >> 6, ll = idx & 63;
        int l = l0 + ll;
        float w = 0.0f;
        if (l < L_) w = (r < 8) ? Wmu[r * L_ + l] : Wsg[(r - 8) * L_ + l];
        ldsW[r * 64 + ll] = w;
    }
    __syncthreads();
    int c = tid & 63, kk = tid >> 6;        // thread owns (c, 4 k's)
    const float* w0 = &ldsW[(kk * 4 + 0) * 64];
    const float* w1 = &ldsW[(kk * 4 + 1) * 64];
    const float* w2 = &ldsW[(kk * 4 + 2) * 64];
    const float* w3 = &ldsW[(kk * 4 + 3) * 64];
    float a0 = 0.f, a1 = 0.f, a2 = 0.f, a3 = 0.f;
    #pragma unroll 8
    for (int l = 0; l < 64; ++l) {
        float a = ldsA[c * 65 + l];
        a0 = fmaf(a, w0[l], a0);
        a1 = fmaf(a, w1[l], a1);
        a2 = fmaf(a, w2[l], a2);
        a3 = fmaf(a, w3[l], a3);
    }
    float* dst = convp + (size_t)lc * 16384 + b * 1024 + c * 16 + kk * 4;
    dst[0] = a0; dst[1] = a1; dst[2] = a2; dst[3] = a3;
}

// K4b: finish conv: sum 61 partials, add bias, exp
__global__ __launch_bounds__(256) void kconvfin(const float* __restrict__ convp,
                                                const float* __restrict__ bmu,
                                                const float* __restrict__ bsg,
                                                float* __restrict__ mus,
                                                float* __restrict__ isig,
                                                float* __restrict__ t1) {
    int o = blockIdx.x * 256 + threadIdx.x;  // 0..16383 = b*1024 + c*16 + kk
    float s = 0.0f;
    #pragma unroll 8
    for (int lc = 0; lc < LCH_; ++lc) s += convp[(size_t)lc * 16384 + o];
    int bc = o >> 4, kk = o & 15;
    int k = kk & 7;
    if (kk < 8) {
        mus[bc * 8 + k] = s + bmu[k];
    } else {
        float logit = s + bsg[k];
        isig[bc * 8 + k] = expf(-logit);
        t1[bc * 8 + k] = -logit - 0.5f * LOG2PI_;
    }
}

// K5: self-normalizing product. Block = (b, l-chunk of 64).
// Reads RAW rep, computes per-l rsqrt(sum_c x^2) in-LDS, folds into product.
__global__ __launch_bounds__(256) void kprod(const float* __restrict__ rep,
                                             const float* __restrict__ mus,
                                             const float* __restrict__ isig,
                                             const float* __restrict__ t1,
                                             float* __restrict__ P,
                                             float* __restrict__ Spart) {
    int b = blockIdx.x / LCH_, lc = blockIdx.x - b * LCH_;
    int l0 = lc * 64;
    __shared__ float ldsA[64 * 65];         // [ll][c], padded
    __shared__ float sc[64];
    __shared__ float ldsMu[512], ldsIs[512], ldsT1[512];
    int tid = threadIdx.x;
    const float4* r4 = (const float4*)rep;
    for (int i4 = tid; i4 < 1024; i4 += 256) {
        int ll = i4 >> 4, c4 = i4 & 15;
        int l = l0 + ll;
        float4 v = make_float4(0.f, 0.f, 0.f, 0.f);
        if (l < L_) {
            int n = l / T_, t = l - n * T_;
            v = r4[(size_t)((b * T_ + t) * N_ + n) * 16 + c4];
        }
        int base = ll * 65 + c4 * 4;
        ldsA[base] = v.x; ldsA[base + 1] = v.y; ldsA[base + 2] = v.z; ldsA[base + 3] = v.w;
    }
    for (int idx = tid; idx < 512; idx += 256) {
        ldsMu[idx] = mus[b * 512 + idx];
        ldsIs[idx] = isig[b * 512 + idx];
        ldsT1[idx] = t1[b * 512 + idx];
    }
    __syncthreads();
    int lane = tid & 63, wv = tid >> 6;
    #pragma unroll 4
    for (int i = 0; i < 16; ++i) {
        int p = wv * 16 + i;
        float x = ldsA[p * 65 + lane];
        float ss = x * x;
        #pragma unroll
        for (int m = 1; m < 64; m <<= 1) ss += __shfl_xor(ss, m);
        if (lane == 0) sc[p] = 1.0f / fmaxf(sqrtf(ss), 1e-12f);
    }
    __syncthreads();
    int l = l0 + lane;
    bool valid = l < L_;
    int k0 = wv * 2, k1 = k0 + 1;
    float scv = sc[lane];
    float p0 = 1.0f, p1 = 1.0f;
    #pragma unroll 8
    for (int c = 0; c < 64; ++c) {
        float a = ldsA[lane * 65 + c] * scv;       // banks (lane+c)%32: 2-way, free
        float z0 = (a - ldsMu[c * 8 + k0]) * ldsIs[c * 8 + k0];
        p0 *= ldsT1[c * 8 + k0] - 0.5f * z0 * z0;
        float z1 = (a - ldsMu[c * 8 + k1]) * ldsIs[c * 8 + k1];
        p1 *= ldsT1[c * 8 + k1] - 0.5f * z1 * z1;
    }
    if (!valid) { p0 = 0.0f; p1 = 0.0f; }
    if (valid) {
        P[(size_t)(b * K_ + k0) * L_ + l] = p0;
        P[(size_t)(b * K_ + k1) * L_ + l] = p1;
    }
    float v0 = p0 * p0, v1 = p1 * p1;
    #pragma unroll
    for (int m = 1; m < 64; m <<= 1) { v0 += __shfl_xor(v0, m); v1 += __shfl_xor(v1, m); }
    if (lane == 0) {
        Spart[(size_t)(b * K_ + k0) * LCH_ + lc] = v0;
        Spart[(size_t)(b * K_ + k1) * LCH_ + lc] = v1;
    }
}

// K5b: finish S: sum 61 chunks -> invn
__global__ void ksfin(const float* __restrict__ Spart, float* __restrict__ invn) {
    int o = threadIdx.x;                    // 128
    float s = 0.0f;
    #pragma unroll 8
    for (int i = 0; i < LCH_; ++i) s += Spart[(size_t)o * LCH_ + i];
    invn[o] = 1.0f / fmaxf(sqrtf(s), 1e-12f);
}

// K6: per-(b,l) LSE over k -> block partials
__global__ __launch_bounds__(256) void kloss(const float* __restrict__ P,
                                             const float* __restrict__ invn,
                                             const float* __restrict__ loggam,
                                             float* __restrict__ part) {
    int b = blockIdx.x >> 4, ch = blockIdx.x & 15;
    int l = ch * 256 + threadIdx.x;
    float ll = 0.0f;
    if (l < L_) {
        float v[K_];
        float mx = -1e30f;
        #pragma unroll
        for (int k = 0; k < K_; ++k) {
            v[k] = P[(size_t)(b * K_ + k) * L_ + l] * invn[b * K_ + k] + loggam[b * K_ + k];
            mx = fmaxf(mx, v[k]);
        }
        float s = 0.0f;
        #pragma unroll
        for (int k = 0; k < K_; ++k) s += expf(v[k] - mx);
        ll = mx + logf(s);
    }
    #pragma unroll
    for (int m = 1; m < 64; m <<= 1) ll += __shfl_xor(ll, m);
    __shared__ float red[4];
    int lane = threadIdx.x & 63, wave = threadIdx.x >> 6;
    if (lane == 0) red[wave] = ll;
    __syncthreads();
    if (threadIdx.x == 0) part[blockIdx.x] = red[0] + red[1] + red[2] + red[3];
}

// K7: final reduce
__global__ void kfinal(const float* __restrict__ part, float* __restrict__ out) {
    double v = (double)part[threadIdx.x];
    #pragma unroll
    for (int m = 1; m < 64; m <<= 1) v += __shfl_xor(v, m);
    __shared__ double red[4];
    int lane = threadIdx.x & 63, wave = threadIdx.x >> 6;
    if (lane == 0) red[wave] = v;
    __syncthreads();
    if (threadIdx.x == 0)
        out[0] = (float)(-(red[0] + red[1] + red[2] + red[3]) / ((double)B_ * (double)L_));
}

extern "C" void kernel_launch(void* const* d_in, const int* in_sizes, int n_in,
                              void* d_out, int out_size, void* d_ws, size_t ws_size,
                              hipStream_t stream) {
    const float* rep     = (const float*)d_in[0];
    const float* rep_aug = (const float*)d_in[1];
    const float* Wg      = (const float*)d_in[2];
    const float* Wmu     = (const float*)d_in[3];
    const float* bmu     = (const float*)d_in[4];
    const float* Wsg     = (const float*)d_in[5];
    const float* bsg     = (const float*)d_in[6];
    float* out = (float*)d_out;
    float* ws  = (float*)d_ws;

    float* loggam = ws + OFF_LOGGAM;
    float* invn   = ws + OFF_INVN;
    float* part   = ws + OFF_PART;
    float* mus    = ws + OFF_MUS;
    float* isig   = ws + OFF_ISIG;
    float* t1     = ws + OFF_T1;
    float* Spart  = ws + OFF_SPART;
    float* P      = ws + OFF_P;
    float* Aaug   = ws + OFF_AAUG;
    float* gpartT = ws + OFF_GPART;
    float* convp  = ws + OFF_CONVP;

    // no memset needed: every workspace cell is overwritten deterministically

    knorm<<<B_ * NGRP_, 256, 0, stream>>>(rep_aug, Aaug);
    kgamma<<<975, 256, 0, stream>>>(Aaug, Wg, gpartT);
    kgsm<<<16, 512, 0, stream>>>(gpartT, loggam);
    kconv<<<B_ * LCH_, 256, 0, stream>>>(Aaug, Wmu, Wsg, convp);
    kconvfin<<<64, 256, 0, stream>>>(convp, bmu, bsg, mus, isig, t1);
    kprod<<<B_ * LCH_, 256, 0, stream>>>(rep, mus, isig, t1, P, Spart);
    ksfin<<<1, 128, 0, stream>>>(Spart, invn);
    kloss<<<B_ * 16, 256, 0, stream>>>(P, invn, loggam, part);
    kfinal<<<1, 256, 0, stream>>>(part, out);
}

// Round 5
// 59.721 us; speedup vs baseline: 2.1204x; 1.4249x over previous
//
#include <hip/hip_runtime.h>
#include <hip/hip_bf16.h>
#include <math.h>

#define B_ 16
#define T_ 12
#define N_ 325
#define C_ 64
#define K_ 8
#define L_ 3900            // N_*T_
#define M_ 249600          // C_*L_
#define M4_ 62400          // M_/4
#define LCH_ 61            // ceil(L_/64)
#define LOG2PI_ 1.8378770664093453f

// ---------------- workspace layout (floats) ----------------
#define OFF_LOGGAM 0            // 128
#define OFF_PART   128          // 256
#define OFF_MUS    384          // 8192
#define OFF_ISIG   8576        // 8192
#define OFF_T1     16768        // 8192
#define OFF_SPART  24960        // 7808 = 128*61
#define OFF_P      32768        // 499200 = B*K*L
#define OFF_AAUG   531968       // 3993600 = B*C*L
#define OFF_GPART  4525568      // 124800 = 128*975 (transposed)
#define OFF_CONVP  4650368      // 998400 = 61*16384
// total = 5648768 floats = 22.6 MB

// kA: per (b, l-chunk 64): stage raw rep_aug tile, L2-normalize over C in-LDS,
//     write normalized transposed Aaug chunk AND conv partials.
__global__ __launch_bounds__(256) void kA(const float* __restrict__ rep_aug,
                                          const float* __restrict__ Wmu,
                                          const float* __restrict__ Wsg,
                                          float* __restrict__ Aaug,
                                          float* __restrict__ convp) {
    int b = blockIdx.x / LCH_, lc = blockIdx.x - b * LCH_;
    int l0 = lc * 64;
    __shared__ float ldsA[64 * 65];      // [ll][c]
    __shared__ float sc[64];
    __shared__ float ldsW[16 * 64];
    int tid = threadIdx.x, lane = tid & 63, wv = tid >> 6;
    const float4* r4 = (const float4*)rep_aug;
    for (int i4 = tid; i4 < 1024; i4 += 256) {
        int ll = i4 >> 4, c4 = i4 & 15;
        int l = l0 + ll;
        float4 v = make_float4(0.f, 0.f, 0.f, 0.f);
        if (l < L_) {
            int n = l / T_, t = l - n * T_;
            v = r4[(size_t)((b * T_ + t) * N_ + n) * 16 + c4];
        }
        int base = ll * 65 + c4 * 4;
        ldsA[base] = v.x; ldsA[base+1] = v.y; ldsA[base+2] = v.z; ldsA[base+3] = v.w;
    }
    for (int idx = tid; idx < 1024; idx += 256) {
        int r = idx >> 6, ll = idx & 63;
        int l = l0 + ll;
        float w = 0.0f;
        if (l < L_) w = (r < 8) ? Wmu[r * L_ + l] : Wsg[(r - 8) * L_ + l];
        ldsW[r * 64 + ll] = w;
    }
    __syncthreads();
    #pragma unroll 4
    for (int i = 0; i < 16; ++i) {
        int p = wv * 16 + i;
        float x = ldsA[p * 65 + lane];
        float ss = x * x;
        #pragma unroll
        for (int m = 1; m < 64; m <<= 1) ss += __shfl_xor(ss, m);
        if (lane == 0) sc[p] = 1.0f / fmaxf(sqrtf(ss), 1e-12f);
    }
    __syncthreads();
    // write normalized transposed chunk: 64 consecutive floats per c row
    for (int idx = tid; idx < 4096; idx += 256) {
        int c = idx >> 6, ll = idx & 63;
        int l = l0 + ll;
        if (l < L_)
            Aaug[(size_t)(b * C_ + c) * L_ + l] = ldsA[ll * 65 + c] * sc[ll];
    }
    // conv partials: thread owns (c, 4 k's)
    int c = lane, kk = wv;
    const float* w0 = &ldsW[(kk * 4 + 0) * 64];
    const float* w1 = &ldsW[(kk * 4 + 1) * 64];
    const float* w2 = &ldsW[(kk * 4 + 2) * 64];
    const float* w3 = &ldsW[(kk * 4 + 3) * 64];
    float a0 = 0.f, a1 = 0.f, a2 = 0.f, a3 = 0.f;
    #pragma unroll 8
    for (int l = 0; l < 64; ++l) {
        float a = ldsA[l * 65 + c] * sc[l];
        a0 = fmaf(a, w0[l], a0);
        a1 = fmaf(a, w1[l], a1);
        a2 = fmaf(a, w2[l], a2);
        a3 = fmaf(a, w3[l], a3);
    }
    float* dst = convp + (size_t)lc * 16384 + b * 1024 + c * 16 + kk * 4;
    dst[0] = a0; dst[1] = a1; dst[2] = a2; dst[3] = a3;
}

// kB: gamma logit partials (blocks 0..974) + convfin (blocks 975..1038)
__global__ __launch_bounds__(256) void kB(const float* __restrict__ Aaug,
                                          const float* __restrict__ Wg,
                                          const float* __restrict__ convp,
                                          const float* __restrict__ bmu,
                                          const float* __restrict__ bsg,
                                          float* __restrict__ gpartT,
                                          float* __restrict__ mus,
                                          float* __restrict__ isig,
                                          float* __restrict__ t1) {
    int tid = threadIdx.x, lane = tid & 63, wv = tid >> 6;
    if (blockIdx.x < 975) {
        const float4* A4 = (const float4*)Aaug;
        const float4* W4 = (const float4*)Wg;
        int m4 = blockIdx.x * 64 + lane;
        float4 w[K_];
        #pragma unroll
        for (int k = 0; k < K_; ++k) w[k] = W4[(size_t)k * M4_ + m4];
        float acc[4][K_];
        #pragma unroll
        for (int bb = 0; bb < 4; ++bb) {
            float4 a = A4[(size_t)(wv * 4 + bb) * M4_ + m4];
            #pragma unroll
            for (int k = 0; k < K_; ++k)
                acc[bb][k] = a.x * w[k].x + a.y * w[k].y + a.z * w[k].z + a.w * w[k].w;
        }
        __shared__ float red[128];
        #pragma unroll
        for (int bb = 0; bb < 4; ++bb)
            #pragma unroll
            for (int k = 0; k < K_; ++k) {
                float v = acc[bb][k];
                #pragma unroll
                for (int m = 1; m < 64; m <<= 1) v += __shfl_xor(v, m);
                if (lane == 0) red[wv * 32 + bb * 8 + k] = v;
            }
        __syncthreads();
        if (tid < 128) gpartT[(size_t)tid * 975 + blockIdx.x] = red[tid];
    } else {
        int o = (blockIdx.x - 975) * 256 + tid;     // 0..16383
        float s = 0.0f;
        #pragma unroll 8
        for (int lc = 0; lc < LCH_; ++lc) s += convp[(size_t)lc * 16384 + o];
        int bc = o >> 4, kk = o & 15, k = kk & 7;
        if (kk < 8) {
            mus[bc * 8 + k] = s + bmu[k];
        } else {
            float logit = s + bsg[k];
            isig[bc * 8 + k] = expf(-logit);
            t1[bc * 8 + k] = -logit - 0.5f * LOG2PI_;
        }
    }
}

// kC: gamma log-softmax (blocks 0..15) + prod (blocks 16..991)
__global__ __launch_bounds__(256) void kC(const float* __restrict__ rep,
                                          const float* __restrict__ gpartT,
                                          const float* __restrict__ mus,
                                          const float* __restrict__ isig,
                                          const float* __restrict__ t1,
                                          float* __restrict__ loggam,
                                          float* __restrict__ P,
                                          float* __restrict__ Spart) {
    int tid = threadIdx.x, lane = tid & 63, wv = tid >> 6;
    if (blockIdx.x < 16) {
        int b = blockIdx.x;
        int k = tid >> 5, i5 = tid & 31;
        float s = 0.0f;
        for (int i = i5; i < 975; i += 32) s += gpartT[(size_t)(b * 8 + k) * 975 + i];
        #pragma unroll
        for (int m = 1; m < 32; m <<= 1) s += __shfl_xor(s, m);
        __shared__ float red[8];
        if (i5 == 0) red[k] = s;
        __syncthreads();
        if (tid < 8) {
            float mx = -1e30f;
            #pragma unroll
            for (int j = 0; j < 8; ++j) mx = fmaxf(mx, red[j]);
            float sum = 0.0f;
            #pragma unroll
            for (int j = 0; j < 8; ++j) sum += expf(red[j] - mx);
            loggam[b * 8 + tid] = red[tid] - mx - logf(sum);
        }
    } else {
        int j = blockIdx.x - 16;
        int b = j / LCH_, lc = j - b * LCH_;
        int l0 = lc * 64;
        __shared__ float ldsA[64 * 65];
        __shared__ float sc[64];
        __shared__ float ldsMu[512], ldsIs[512], ldsT1[512];
        const float4* r4 = (const float4*)rep;
        for (int i4 = tid; i4 < 1024; i4 += 256) {
            int ll = i4 >> 4, c4 = i4 & 15;
            int l = l0 + ll;
            float4 v = make_float4(0.f, 0.f, 0.f, 0.f);
            if (l < L_) {
                int n = l / T_, t = l - n * T_;
                v = r4[(size_t)((b * T_ + t) * N_ + n) * 16 + c4];
            }
            int base = ll * 65 + c4 * 4;
            ldsA[base] = v.x; ldsA[base+1] = v.y; ldsA[base+2] = v.z; ldsA[base+3] = v.w;
        }
        for (int idx = tid; idx < 512; idx += 256) {
            ldsMu[idx] = mus[b * 512 + idx];
            ldsIs[idx] = isig[b * 512 + idx];
            ldsT1[idx] = t1[b * 512 + idx];
        }
        __syncthreads();
        #pragma unroll 4
        for (int i = 0; i < 16; ++i) {
            int p = wv * 16 + i;
            float x = ldsA[p * 65 + lane];
            float ss = x * x;
            #pragma unroll
            for (int m = 1; m < 64; m <<= 1) ss += __shfl_xor(ss, m);
            if (lane == 0) sc[p] = 1.0f / fmaxf(sqrtf(ss), 1e-12f);
        }
        __syncthreads();
        int l = l0 + lane;
        bool valid = l < L_;
        int k0 = wv * 2, k1 = k0 + 1;
        float scv = sc[lane];
        float p0 = 1.0f, p1 = 1.0f;
        #pragma unroll 8
        for (int c = 0; c < 64; ++c) {
            float a = ldsA[lane * 65 + c] * scv;
            float z0 = (a - ldsMu[c * 8 + k0]) * ldsIs[c * 8 + k0];
            p0 *= ldsT1[c * 8 + k0] - 0.5f * z0 * z0;
            float z1 = (a - ldsMu[c * 8 + k1]) * ldsIs[c * 8 + k1];
            p1 *= ldsT1[c * 8 + k1] - 0.5f * z1 * z1;
        }
        if (!valid) { p0 = 0.0f; p1 = 0.0f; }
        if (valid) {
            P[(size_t)(b * K_ + k0) * L_ + l] = p0;
            P[(size_t)(b * K_ + k1) * L_ + l] = p1;
        }
        float v0 = p0 * p0, v1 = p1 * p1;
        #pragma unroll
        for (int m = 1; m < 64; m <<= 1) { v0 += __shfl_xor(v0, m); v1 += __shfl_xor(v1, m); }
        if (lane == 0) {
            Spart[(size_t)(b * K_ + k0) * LCH_ + lc] = v0;
            Spart[(size_t)(b * K_ + k1) * LCH_ + lc] = v1;
        }
    }
}

// kD: per-(b, 256-l chunk): finish invn from Spart, LSE over k, block partial
__global__ __launch_bounds__(256) void kD(const float* __restrict__ P,
                                          const float* __restrict__ Spart,
                                          const float* __restrict__ loggam,
                                          float* __restrict__ part) {
    int b = blockIdx.x >> 4, ch = blockIdx.x & 15;
    int tid = threadIdx.x, lane = tid & 63, wv = tid >> 6;
    __shared__ float invk[8], lgk[8];
    if (tid < 8) {
        float s = 0.0f;
        #pragma unroll 8
        for (int i = 0; i < LCH_; ++i) s += Spart[(size_t)(b * 8 + tid) * LCH_ + i];
        invk[tid] = 1.0f / fmaxf(sqrtf(s), 1e-12f);
        lgk[tid] = loggam[b * 8 + tid];
    }
    __syncthreads();
    int l = ch * 256 + tid;
    float ll = 0.0f;
    if (l < L_) {
        float v[K_];
        float mx = -1e30f;
        #pragma unroll
        for (int k = 0; k < K_; ++k) {
            v[k] = P[(size_t)(b * K_ + k) * L_ + l] * invk[k] + lgk[k];
            mx = fmaxf(mx, v[k]);
        }
        float s = 0.0f;
        #pragma unroll
        for (int k = 0; k < K_; ++k) s += expf(v[k] - mx);
        ll = mx + logf(s);
    }
    #pragma unroll
    for (int m = 1; m < 64; m <<= 1) ll += __shfl_xor(ll, m);
    __shared__ float red[4];
    if (lane == 0) red[wv] = ll;
    __syncthreads();
    if (tid == 0) part[blockIdx.x] = red[0] + red[1] + red[2] + red[3];
}

// kE: final reduce
__global__ void kE(const float* __restrict__ part, float* __restrict__ out) {
    double v = (double)part[threadIdx.x];
    #pragma unroll
    for (int m = 1; m < 64; m <<= 1) v += __shfl_xor(v, m);
    __shared__ double red[4];
    int lane = threadIdx.x & 63, wave = threadIdx.x >> 6;
    if (lane == 0) red[wave] = v;
    __syncthreads();
    if (threadIdx.x == 0)
        out[0] = (float)(-(red[0] + red[1] + red[2] + red[3]) / ((double)B_ * (double)L_));
}

extern "C" void kernel_launch(void* const* d_in, const int* in_sizes, int n_in,
                              void* d_out, int out_size, void* d_ws, size_t ws_size,
                              hipStream_t stream) {
    const float* rep     = (const float*)d_in[0];
    const float* rep_aug = (const float*)d_in[1];
    const float* Wg      = (const float*)d_in[2];
    const float* Wmu     = (const float*)d_in[3];
    const float* bmu     = (const float*)d_in[4];
    const float* Wsg     = (const float*)d_in[5];
    const float* bsg     = (const float*)d_in[6];
    float* out = (float*)d_out;
    float* ws  = (float*)d_ws;

    float* loggam = ws + OFF_LOGGAM;
    float* part   = ws + OFF_PART;
    float* mus    = ws + OFF_MUS;
    float* isig   = ws + OFF_ISIG;
    float* t1     = ws + OFF_T1;
    float* Spart  = ws + OFF_SPART;
    float* P      = ws + OFF_P;
    float* Aaug   = ws + OFF_AAUG;
    float* gpartT = ws + OFF_GPART;
    float* convp  = ws + OFF_CONVP;

    kA<<<B_ * LCH_, 256, 0, stream>>>(rep_aug, Wmu, Wsg, Aaug, convp);
    kB<<<975 + 64, 256, 0, stream>>>(Aaug, Wg, convp, bmu, bsg, gpartT, mus, isig, t1);
    kC<<<16 + B_ * LCH_, 256, 0, stream>>>(rep, gpartT, mus, isig, t1, loggam, P, Spart);
    kD<<<B_ * 16, 256, 0, stream>>>(P, Spart, loggam, part);
    kE<<<1, 256, 0, stream>>>(part, out);
}